// Round 2
// baseline (3527.465 us; speedup 1.0000x reference)
//
#include <hip/hip_runtime.h>

// Problem constants
#define BATCH   32
#define CPD     64
#define TSTEPS  1024
#define IN_DIM  256
#define HID     512
#define WIN     1024

typedef _Float16 half2_t __attribute__((ext_vector_type(2)));
typedef _Float16 f16x8   __attribute__((ext_vector_type(8)));
typedef float    f32x4   __attribute__((ext_vector_type(4)));

__device__ __forceinline__ float tanh_fast(float x) {
    // tanh(x) = 1 - 2/(e^{2x}+1); exact at +-inf, ~1e-7 abs err in range
    float e = __expf(2.0f * x);
    return 1.0f - 2.0f / (e + 1.0f);
}

// ---------------- A1: M_t[h][c] = sum_i proj[c][i] * W_ih[h][i] ----------------
__global__ __launch_bounds__(512) void k_a1(const float* __restrict__ proj,
                                            const float* __restrict__ W_ih,
                                            float* __restrict__ M_t) {
    __shared__ float p[IN_DIM];
    int c = blockIdx.x;                       // 64 blocks
    if (threadIdx.x < IN_DIM) p[threadIdx.x] = proj[c * IN_DIM + threadIdx.x];
    __syncthreads();
    int h = threadIdx.x;                      // 512 threads
    const float4* wr = (const float4*)(W_ih + (size_t)h * IN_DIM);
    float acc = 0.f;
#pragma unroll
    for (int i = 0; i < IN_DIM / 4; ++i) {
        float4 v = wr[i];
        acc += v.x * p[4*i] + v.y * p[4*i+1] + v.z * p[4*i+2] + v.w * p[4*i+3];
    }
    M_t[(size_t)h * CPD + c] = acc;           // [512][64]
}

// ---------------- C0: convert W_out f32 -> f16 ----------------
__global__ __launch_bounds__(256) void k_cvt(const float* __restrict__ src,
                                             _Float16* __restrict__ dst) {
    int i = (blockIdx.x * 256 + threadIdx.x) * 4;   // 512 blocks covers 524288
    float4 v = *(const float4*)(src + i);
    dst[i+0] = (_Float16)v.x; dst[i+1] = (_Float16)v.y;
    dst[i+2] = (_Float16)v.z; dst[i+3] = (_Float16)v.w;
}

// ---------------- A2: xw[b][t][h] = sum_c control[b][c][t] * M_t[h][c] ----------------
__global__ __launch_bounds__(512) void k_a2(const float* __restrict__ control,
                                            const float* __restrict__ M_t,
                                            float* __restrict__ xw) {
    __shared__ float ctl[CPD][68];            // padded, 16B-aligned rows
    int b  = blockIdx.x >> 4;                 // 32 batches
    int t0 = (blockIdx.x & 15) * 64;          // 16 t-blocks of 64
    int tid = threadIdx.x;                    // 512 threads

    // stage control tile (64 c x 64 t), coalesced float4 along t
    const float* gb = control + (size_t)b * CPD * TSTEPS + t0;
#pragma unroll
    for (int i = 0; i < 2; ++i) {
        int flat4 = tid * 2 + i;              // 0..1023 quads
        int c = flat4 >> 4, t4 = (flat4 & 15) * 4;
        float4 v = *(const float4*)(gb + (size_t)c * TSTEPS + t4);
        *(float4*)&ctl[c][t4] = v;
    }
    // M row into regs
    int h = tid;
    float mrow[CPD];
    const float4* mp = (const float4*)(M_t + (size_t)h * CPD);
#pragma unroll
    for (int i = 0; i < CPD / 4; ++i) {
        float4 v = mp[i];
        mrow[4*i] = v.x; mrow[4*i+1] = v.y; mrow[4*i+2] = v.z; mrow[4*i+3] = v.w;
    }
    __syncthreads();

    float* xo = xw + ((size_t)b * TSTEPS + t0) * HID + h;
#pragma unroll
    for (int half = 0; half < 2; ++half) {
        float acc[32];
#pragma unroll
        for (int q = 0; q < 32; ++q) acc[q] = 0.f;
#pragma unroll
        for (int c = 0; c < CPD; ++c) {
            float m = mrow[c];
#pragma unroll
            for (int q = 0; q < 8; ++q) {
                float4 v = *(const float4*)&ctl[c][half * 32 + q * 4];  // broadcast read
                acc[q*4+0] += v.x * m; acc[q*4+1] += v.y * m;
                acc[q*4+2] += v.z * m; acc[q*4+3] += v.w * m;
            }
        }
#pragma unroll
        for (int tt = 0; tt < 32; ++tt)
            xo[(size_t)(half * 32 + tt) * HID] = acc[tt];
    }
}

// ---------------- B: sequential recurrence, one WG per batch ----------------
// 32 WGs x 1024 threads. Thread (rb = tid>>4, cs = tid&15) owns W rows
// [rb*8, rb*8+8) x cols [cs*32, cs*32+32) in 128 half2 VGPRs. Per step:
// 128 fdot2 -> distributed shuffle reduce (8 shuffles) -> tanh -> LDS
// double-buffer exchange with ONE barrier. No cross-WG communication.
__global__ __launch_bounds__(1024) void k_scan(const float* __restrict__ W_hh,
                                               const float* __restrict__ xw,
                                               _Float16* __restrict__ hs) {
    const int b    = blockIdx.x;
    const int tid  = threadIdx.x;
    const int cs   = tid & 15;                // col slice
    const int rb   = tid >> 4;                // row block (8 rows)
    const int lane = tid & 63;
    const int w    = tid >> 6;                // wave 0..15

    // ---- weights into VGPRs: wreg[j][q] = W[rb*8+j][cs*32+2q .. +1] (f16) ----
    half2_t wreg[8][16];
#pragma unroll
    for (int j = 0; j < 8; ++j) {
        const float* src = W_hh + (size_t)(rb * 8 + j) * HID + cs * 32;
#pragma unroll
        for (int q = 0; q < 16; q += 2) {
            float4 f = *(const float4*)(src + 2 * q);
            wreg[j][q]     = (half2_t){(_Float16)f.x, (_Float16)f.y};
            wreg[j][q + 1] = (half2_t){(_Float16)f.z, (_Float16)f.w};
        }
    }

    // h double buffer: 16 chunks of 32 halves, stride 40 halves (80 B) so the
    // 16 b128 read-lines cycle bank-groups mod 8 (2-way conflict = free).
    __shared__ __align__(16) _Float16 hb[2][16 * 40];

    // After the reduce, lane l of wave w holds the sum for this row:
    const int myrow  = w * 32 + ((lane >> 4) << 3) + (lane & 7);  // dup at lane^8
    const bool writer = !(lane & 8);
    const bool b0 = lane & 1, b1 = lane & 2, b2 = lane & 4;

    const float* xwb = xw + (size_t)b * TSTEPS * HID;
    _Float16*    hsb = hs + (size_t)b * TSTEPS * HID;

    // ---- t = 0: h0 = tanh(xw[0]) ----
    {
        float h0 = tanh_fast(xwb[myrow]);
        _Float16 hf = (_Float16)h0;
        if (writer) {
            hb[0][w * 40 + (myrow & 31)] = hf;
            hsb[myrow] = hf;
        }
    }
    __syncthreads();

#pragma unroll 1
    for (int t = 1; t < TSTEPS; ++t) {
        // prefetch xw[t][myrow] (consumed ~700 cycles later, after the dot)
        float xwv = xwb[(size_t)t * HID + myrow];

        // read h_{t-1} chunk cs: 4 x ds_read_b128
        const _Float16* rp = &hb[(t + 1) & 1][cs * 40];
        f16x8 hv0 = *(const f16x8*)(rp);
        f16x8 hv1 = *(const f16x8*)(rp + 8);
        f16x8 hv2 = *(const f16x8*)(rp + 16);
        f16x8 hv3 = *(const f16x8*)(rp + 24);
        half2_t h2[16];
#pragma unroll
        for (int q = 0; q < 4; ++q) {
            h2[q]      = (half2_t){hv0[2 * q], hv0[2 * q + 1]};
            h2[4 + q]  = (half2_t){hv1[2 * q], hv1[2 * q + 1]};
            h2[8 + q]  = (half2_t){hv2[2 * q], hv2[2 * q + 1]};
            h2[12 + q] = (half2_t){hv3[2 * q], hv3[2 * q + 1]};
        }

        // ---- dot: a[j] = W[rb*8+j][cs*32..+32) . h[cs*32..+32) ----
        float a[8];
#pragma unroll
        for (int j = 0; j < 8; ++j) a[j] = 0.f;
#pragma unroll
        for (int q = 0; q < 16; ++q) {
#pragma unroll
            for (int j = 0; j < 8; ++j)
                a[j] = __builtin_amdgcn_fdot2(wreg[j][q], h2[q], a[j], false);
        }

        // ---- distributed split-reduce over the 16 col-slices (8 shuffles) ----
        // s1 xor1: a[j] <- tree 2j + b0
#pragma unroll
        for (int j = 0; j < 4; ++j) {
            float snd = b0 ? a[2 * j] : a[2 * j + 1];
            float kp  = b0 ? a[2 * j + 1] : a[2 * j];
            a[j] = kp + __shfl_xor(snd, 1, 64);
        }
        // s2 xor2: a[j] <- tree 4j + 2b1 + b0
#pragma unroll
        for (int j = 0; j < 2; ++j) {
            float snd = b1 ? a[2 * j] : a[2 * j + 1];
            float kp  = b1 ? a[2 * j + 1] : a[2 * j];
            a[j] = kp + __shfl_xor(snd, 2, 64);
        }
        // s3 xor4: a[0] <- tree 4b2 + 2b1 + b0  (= lane&7)
        {
            float snd = b2 ? a[0] : a[1];
            float kp  = b2 ? a[1] : a[0];
            a[0] = kp + __shfl_xor(snd, 4, 64);
        }
        // s4 xor8: combine the duplicated octet halves
        a[0] += __shfl_xor(a[0], 8, 64);

        // ---- activation + publish ----
        float hval = tanh_fast(a[0] + xwv);
        _Float16 hfv = (_Float16)hval;
        if (writer) {
            hb[t & 1][w * 40 + (myrow & 31)] = hfv;
            hsb[(size_t)t * HID + myrow] = hfv;
        }
        __syncthreads();
    }
}

// ---------------- C: out[row][w] = sin( sum_h hs[row][h] * Wout[w][h] ) ----------------
// 128x128 tile, BK=32, 4 waves in 2x2 quadrants, f16 MFMA 16x16x32.
// Grid is (N-tiles, M-tiles) so consecutive blocks share the A panel (L2 reuse).
__global__ void k_outgemm(const _Float16* __restrict__ hs,
                          const _Float16* __restrict__ Wo,
                          float* __restrict__ out) {
    __shared__ _Float16 Ap[128][40];          // +8 pad: conflict-free frag reads
    __shared__ _Float16 Bp[128][40];
    int tid = threadIdx.x;
    int r0 = blockIdx.y * 128;                // 256 M-tiles
    int c0 = blockIdx.x * 128;                // 8 N-tiles
    int wid = tid >> 6, l = tid & 63;
    int wr = (wid >> 1) * 64, wc = (wid & 1) * 64;
    int lrow = tid & 127, lhalf = (tid >> 7) * 16;   // staging assignment
    int fr = l & 15, kg = (l >> 4) * 8;

    f32x4 acc[4][4];
#pragma unroll
    for (int m = 0; m < 4; ++m)
#pragma unroll
        for (int n = 0; n < 4; ++n) acc[m][n] = (f32x4){0.f, 0.f, 0.f, 0.f};

    for (int k0 = 0; k0 < HID; k0 += 32) {
        const uint4* ga = (const uint4*)(hs + (size_t)(r0 + lrow) * HID + k0 + lhalf);
        uint4 a0 = ga[0], a1 = ga[1];
        const uint4* gbp = (const uint4*)(Wo + (size_t)(c0 + lrow) * HID + k0 + lhalf);
        uint4 b0 = gbp[0], b1 = gbp[1];
        __syncthreads();                      // prev-iter reads done
        *(uint4*)&Ap[lrow][lhalf] = a0; *(uint4*)&Ap[lrow][lhalf + 8] = a1;
        *(uint4*)&Bp[lrow][lhalf] = b0; *(uint4*)&Bp[lrow][lhalf + 8] = b1;
        __syncthreads();

        f16x8 af[4], bf[4];
#pragma unroll
        for (int m = 0; m < 4; ++m) af[m] = *(const f16x8*)&Ap[wr + m * 16 + fr][kg];
#pragma unroll
        for (int n = 0; n < 4; ++n) bf[n] = *(const f16x8*)&Bp[wc + n * 16 + fr][kg];
#pragma unroll
        for (int m = 0; m < 4; ++m)
#pragma unroll
            for (int n = 0; n < 4; ++n)
                acc[m][n] = __builtin_amdgcn_mfma_f32_16x16x32_f16(af[m], bf[n], acc[m][n], 0, 0, 0);
    }

    int fq = l >> 4;
#pragma unroll
    for (int m = 0; m < 4; ++m)
#pragma unroll
        for (int n = 0; n < 4; ++n)
#pragma unroll
            for (int q = 0; q < 4; ++q) {
                int row = r0 + wr + m * 16 + fq * 4 + q;
                int col = c0 + wc + n * 16 + fr;
                out[(size_t)row * WIN + col] = __sinf(acc[m][n][q]);
            }
}

// ---------------- launch ----------------
extern "C" void kernel_launch(void* const* d_in, const int* in_sizes, int n_in,
                              void* d_out, int out_size, void* d_ws, size_t ws_size,
                              hipStream_t stream) {
    const float* control = (const float*)d_in[0];  // (32, 64, 1024)
    const float* proj    = (const float*)d_in[1];  // (64, 256)
    const float* W_ih    = (const float*)d_in[2];  // (512, 256)
    const float* W_hh    = (const float*)d_in[3];  // (512, 512)
    const float* W_out   = (const float*)d_in[4];  // (1024, 512)
    float* out = (float*)d_out;                    // 32 * 1024 * 1024 f32

    // workspace carve
    const size_t XW_B   = (size_t)BATCH * TSTEPS * HID * 4;     // 64 MiB
    const size_t MT_B   = (size_t)HID * CPD * 4;                // 128 KiB
    const size_t HS_B   = (size_t)BATCH * TSTEPS * HID * 2;     // 32 MiB
    const size_t WO_B   = (size_t)WIN * HID * 2;                // 1 MiB
    if (ws_size < XW_B + MT_B + HS_B + WO_B) return;

    char* ws = (char*)d_ws;
    float* xw = (float*)ws;                          ws += XW_B;
    float* M_t = (float*)ws;                         ws += MT_B;
    _Float16* hs = (_Float16*)ws;                    ws += HS_B;
    _Float16* Wo = (_Float16*)ws;

    k_a1<<<CPD, 512, 0, stream>>>(proj, W_ih, M_t);
    k_cvt<<<512, 256, 0, stream>>>(W_out, Wo);
    k_a2<<<BATCH * 16, 512, 0, stream>>>(control, M_t, xw);
    k_scan<<<BATCH, 1024, 0, stream>>>(W_hh, xw, hs);
    k_outgemm<<<dim3(8, 256), 256, 0, stream>>>(hs, Wo, out);
}

// Round 3
// 2115.510 us; speedup vs baseline: 1.6674x; 1.6674x over previous
//
#include <hip/hip_runtime.h>

// Problem constants
#define BATCH   32
#define CPD     64
#define TSTEPS  1024
#define IN_DIM  256
#define HID     512
#define WIN     1024

typedef _Float16 half2_t __attribute__((ext_vector_type(2)));
typedef _Float16 f16x8   __attribute__((ext_vector_type(8)));
typedef float    f32x4   __attribute__((ext_vector_type(4)));

union F16x8U { f16x8 v; half2_t p[4]; };

__device__ __forceinline__ float tanh_fast(float x) {
    // tanh(x) = 1 - 2/(e^{2x}+1); exact at +-inf, ~1e-7 abs err in range
    float e = __expf(2.0f * x);
    return 1.0f - 2.0f / (e + 1.0f);
}

// ---------------- A1: M_t[h][c] = sum_i proj[c][i] * W_ih[h][i] ----------------
__global__ __launch_bounds__(512) void k_a1(const float* __restrict__ proj,
                                            const float* __restrict__ W_ih,
                                            float* __restrict__ M_t) {
    __shared__ float p[IN_DIM];
    int c = blockIdx.x;                       // 64 blocks
    if (threadIdx.x < IN_DIM) p[threadIdx.x] = proj[c * IN_DIM + threadIdx.x];
    __syncthreads();
    int h = threadIdx.x;                      // 512 threads
    const float4* wr = (const float4*)(W_ih + (size_t)h * IN_DIM);
    float acc = 0.f;
#pragma unroll
    for (int i = 0; i < IN_DIM / 4; ++i) {
        float4 v = wr[i];
        acc += v.x * p[4*i] + v.y * p[4*i+1] + v.z * p[4*i+2] + v.w * p[4*i+3];
    }
    M_t[(size_t)h * CPD + c] = acc;           // [512][64]
}

// ---------------- C0: convert W_out f32 -> f16 ----------------
__global__ __launch_bounds__(256) void k_cvt(const float* __restrict__ src,
                                             _Float16* __restrict__ dst) {
    int i = (blockIdx.x * 256 + threadIdx.x) * 4;   // 512 blocks covers 524288
    float4 v = *(const float4*)(src + i);
    dst[i+0] = (_Float16)v.x; dst[i+1] = (_Float16)v.y;
    dst[i+2] = (_Float16)v.z; dst[i+3] = (_Float16)v.w;
}

// ---------------- A2: xw[b][t][h] = sum_c control[b][c][t] * M_t[h][c] ----------------
__global__ __launch_bounds__(512) void k_a2(const float* __restrict__ control,
                                            const float* __restrict__ M_t,
                                            float* __restrict__ xw) {
    __shared__ float ctl[CPD][68];            // padded, 16B-aligned rows
    int b  = blockIdx.x >> 4;                 // 32 batches
    int t0 = (blockIdx.x & 15) * 64;          // 16 t-blocks of 64
    int tid = threadIdx.x;                    // 512 threads

    // stage control tile (64 c x 64 t), coalesced float4 along t
    const float* gb = control + (size_t)b * CPD * TSTEPS + t0;
#pragma unroll
    for (int i = 0; i < 2; ++i) {
        int flat4 = tid * 2 + i;              // 0..1023 quads
        int c = flat4 >> 4, t4 = (flat4 & 15) * 4;
        float4 v = *(const float4*)(gb + (size_t)c * TSTEPS + t4);
        *(float4*)&ctl[c][t4] = v;
    }
    // M row into regs
    int h = tid;
    float mrow[CPD];
    const float4* mp = (const float4*)(M_t + (size_t)h * CPD);
#pragma unroll
    for (int i = 0; i < CPD / 4; ++i) {
        float4 v = mp[i];
        mrow[4*i] = v.x; mrow[4*i+1] = v.y; mrow[4*i+2] = v.z; mrow[4*i+3] = v.w;
    }
    __syncthreads();

    float* xo = xw + ((size_t)b * TSTEPS + t0) * HID + h;
#pragma unroll
    for (int half = 0; half < 2; ++half) {
        float acc[32];
#pragma unroll
        for (int q = 0; q < 32; ++q) acc[q] = 0.f;
#pragma unroll
        for (int c = 0; c < CPD; ++c) {
            float m = mrow[c];
#pragma unroll
            for (int q = 0; q < 8; ++q) {
                float4 v = *(const float4*)&ctl[c][half * 32 + q * 4];  // broadcast read
                acc[q*4+0] += v.x * m; acc[q*4+1] += v.y * m;
                acc[q*4+2] += v.z * m; acc[q*4+3] += v.w * m;
            }
        }
#pragma unroll
        for (int tt = 0; tt < 32; ++tt)
            xo[(size_t)(half * 32 + tt) * HID] = acc[tt];
    }
}

// ---------------- B: sequential recurrence, one WG per batch ----------------
// 32 WGs x 1024 threads, __launch_bounds__(1024,4) -> 128 VGPR cap, 1 WG/CU.
// Thread (rb = tid>>4, cs = tid&15) owns W rows [rb*8, rb*8+8) x cols
// [cs*32, cs*32+32). Rows 0..5 live in VGPRs (96 half2); rows 6..7 live in
// LDS (128 KiB, [chunk][tid] f16x8 layout -> conflict-free b128 reads).
// Per step: 128 fdot2 -> distributed shuffle reduce (8 shuffles) -> tanh ->
// LDS double-buffer exchange with ONE barrier. No cross-WG communication.
#define WLDS_CHUNKS 8
#define HB_STRIDE   40
__global__ __launch_bounds__(1024, 4) void k_scan(const float* __restrict__ W_hh,
                                                  const float* __restrict__ xw,
                                                  _Float16* __restrict__ hs) {
    const int b    = blockIdx.x;
    const int tid  = threadIdx.x;
    const int cs   = tid & 15;                // col slice
    const int rb   = tid >> 4;                // row block (8 rows)
    const int lane = tid & 63;
    const int w    = tid >> 6;                // wave 0..15

    // LDS: wlds[8][1024] f16x8 (128 KiB) + h double buffer (2.5 KiB)
    __shared__ __align__(16) f16x8    wlds[WLDS_CHUNKS * 1024];
    __shared__ __align__(16) _Float16 hb[2][16 * HB_STRIDE];

    // ---- rows 0..5 into VGPRs: wreg[j][q] = W[rb*8+j][cs*32+2q..+1] (f16) ----
    half2_t wreg[6][16];
#pragma unroll
    for (int j = 0; j < 6; ++j) {
        const float* src = W_hh + (size_t)(rb * 8 + j) * HID + cs * 32;
#pragma unroll
        for (int q = 0; q < 16; q += 2) {
            float4 f = *(const float4*)(src + 2 * q);
            wreg[j][q]     = (half2_t){(_Float16)f.x, (_Float16)f.y};
            wreg[j][q + 1] = (half2_t){(_Float16)f.z, (_Float16)f.w};
        }
    }
    // ---- rows 6..7 into LDS: chunk rr*4+qq holds cols [qq*8, qq*8+8) ----
#pragma unroll
    for (int rr = 0; rr < 2; ++rr) {
        const float* src = W_hh + (size_t)(rb * 8 + 6 + rr) * HID + cs * 32;
#pragma unroll
        for (int qq = 0; qq < 4; ++qq) {
            float4 f0 = *(const float4*)(src + qq * 8);
            float4 f1 = *(const float4*)(src + qq * 8 + 4);
            F16x8U u;
            u.p[0] = (half2_t){(_Float16)f0.x, (_Float16)f0.y};
            u.p[1] = (half2_t){(_Float16)f0.z, (_Float16)f0.w};
            u.p[2] = (half2_t){(_Float16)f1.x, (_Float16)f1.y};
            u.p[3] = (half2_t){(_Float16)f1.z, (_Float16)f1.w};
            wlds[((rr * 4 + qq) << 10) + tid] = u.v;
        }
    }

    // After the reduce, lane l of wave w holds the sum for this row:
    const int myrow   = w * 32 + ((lane >> 4) << 3) + (lane & 7);  // dup at lane^8
    const bool writer = !(lane & 8);
    const bool b0 = lane & 1, b1 = lane & 2, b2 = lane & 4;

    const float* xwb = xw + (size_t)b * TSTEPS * HID;
    _Float16*    hsb = hs + (size_t)b * TSTEPS * HID;

    // ---- t = 0: h0 = tanh(xw[0]) ----
    {
        float h0 = tanh_fast(xwb[myrow]);
        _Float16 hf = (_Float16)h0;
        if (writer) {
            hb[0][w * HB_STRIDE + (myrow & 31)] = hf;
            hsb[myrow] = hf;
        }
    }
    __syncthreads();

#pragma unroll 1
    for (int t = 1; t < TSTEPS; ++t) {
        // prefetch xw[t][myrow] (consumed after the dot+reduce)
        float xwv = xwb[(size_t)t * HID + myrow];

        const _Float16* rp = &hb[(t + 1) & 1][cs * HB_STRIDE];

        float a[8];
#pragma unroll
        for (int j = 0; j < 8; ++j) a[j] = 0.f;

        // ---- dot: a[j] = W[rb*8+j][cs*32..+32) . h[cs*32..+32) ----
        // h chunk loaded 8 halves at a time; rows 6,7 streamed from LDS.
#pragma unroll
        for (int qq = 0; qq < 4; ++qq) {
            F16x8U hu, w6, w7;
            hu.v = *(const f16x8*)(rp + qq * 8);
            w6.v = wlds[(qq << 10) + tid];
            w7.v = wlds[((4 + qq) << 10) + tid];
#pragma unroll
            for (int q = 0; q < 4; ++q) {
                half2_t hh = hu.p[q];
#pragma unroll
                for (int j = 0; j < 6; ++j)
                    a[j] = __builtin_amdgcn_fdot2(wreg[j][qq * 4 + q], hh, a[j], false);
                a[6] = __builtin_amdgcn_fdot2(w6.p[q], hh, a[6], false);
                a[7] = __builtin_amdgcn_fdot2(w7.p[q], hh, a[7], false);
            }
        }

        // ---- distributed split-reduce over the 16 col-slices (8 shuffles) ----
#pragma unroll
        for (int j = 0; j < 4; ++j) {          // xor1: keep tree 2j + b0
            float snd = b0 ? a[2 * j] : a[2 * j + 1];
            float kp  = b0 ? a[2 * j + 1] : a[2 * j];
            a[j] = kp + __shfl_xor(snd, 1, 64);
        }
#pragma unroll
        for (int j = 0; j < 2; ++j) {          // xor2: tree 4j + 2b1 + b0
            float snd = b1 ? a[2 * j] : a[2 * j + 1];
            float kp  = b1 ? a[2 * j + 1] : a[2 * j];
            a[j] = kp + __shfl_xor(snd, 2, 64);
        }
        {                                      // xor4: tree = lane&7
            float snd = b2 ? a[0] : a[1];
            float kp  = b2 ? a[1] : a[0];
            a[0] = kp + __shfl_xor(snd, 4, 64);
        }
        a[0] += __shfl_xor(a[0], 8, 64);       // combine duplicated octets

        // ---- activation + publish ----
        if (writer) {
            float hval = tanh_fast(a[0] + xwv);
            _Float16 hfv = (_Float16)hval;
            hb[t & 1][w * HB_STRIDE + (myrow & 31)] = hfv;
            hsb[(size_t)t * HID + myrow] = hfv;
        }
        __syncthreads();
    }
}

// ---------------- C: out[row][w] = sin( sum_h hs[row][h] * Wout[w][h] ) ----------------
// 128x128 tile, BK=32, 4 waves in 2x2 quadrants, f16 MFMA 16x16x32.
// Grid is (N-tiles, M-tiles) so consecutive blocks share the A panel (L2 reuse).
__global__ void k_outgemm(const _Float16* __restrict__ hs,
                          const _Float16* __restrict__ Wo,
                          float* __restrict__ out) {
    __shared__ _Float16 Ap[128][40];          // +8 pad: conflict-free frag reads
    __shared__ _Float16 Bp[128][40];
    int tid = threadIdx.x;
    int r0 = blockIdx.y * 128;                // 256 M-tiles
    int c0 = blockIdx.x * 128;                // 8 N-tiles
    int wid = tid >> 6, l = tid & 63;
    int wr = (wid >> 1) * 64, wc = (wid & 1) * 64;
    int lrow = tid & 127, lhalf = (tid >> 7) * 16;   // staging assignment
    int fr = l & 15, kg = (l >> 4) * 8;

    f32x4 acc[4][4];
#pragma unroll
    for (int m = 0; m < 4; ++m)
#pragma unroll
        for (int n = 0; n < 4; ++n) acc[m][n] = (f32x4){0.f, 0.f, 0.f, 0.f};

    for (int k0 = 0; k0 < HID; k0 += 32) {
        const uint4* ga = (const uint4*)(hs + (size_t)(r0 + lrow) * HID + k0 + lhalf);
        uint4 a0 = ga[0], a1 = ga[1];
        const uint4* gbp = (const uint4*)(Wo + (size_t)(c0 + lrow) * HID + k0 + lhalf);
        uint4 b0 = gbp[0], b1 = gbp[1];
        __syncthreads();                      // prev-iter reads done
        *(uint4*)&Ap[lrow][lhalf] = a0; *(uint4*)&Ap[lrow][lhalf + 8] = a1;
        *(uint4*)&Bp[lrow][lhalf] = b0; *(uint4*)&Bp[lrow][lhalf + 8] = b1;
        __syncthreads();

        f16x8 af[4], bf[4];
#pragma unroll
        for (int m = 0; m < 4; ++m) af[m] = *(const f16x8*)&Ap[wr + m * 16 + fr][kg];
#pragma unroll
        for (int n = 0; n < 4; ++n) bf[n] = *(const f16x8*)&Bp[wc + n * 16 + fr][kg];
#pragma unroll
        for (int m = 0; m < 4; ++m)
#pragma unroll
            for (int n = 0; n < 4; ++n)
                acc[m][n] = __builtin_amdgcn_mfma_f32_16x16x32_f16(af[m], bf[n], acc[m][n], 0, 0, 0);
    }

    int fq = l >> 4;
#pragma unroll
    for (int m = 0; m < 4; ++m)
#pragma unroll
        for (int n = 0; n < 4; ++n)
#pragma unroll
            for (int q = 0; q < 4; ++q) {
                int row = r0 + wr + m * 16 + fq * 4 + q;
                int col = c0 + wc + n * 16 + fr;
                out[(size_t)row * WIN + col] = __sinf(acc[m][n][q]);
            }
}

// ---------------- launch ----------------
extern "C" void kernel_launch(void* const* d_in, const int* in_sizes, int n_in,
                              void* d_out, int out_size, void* d_ws, size_t ws_size,
                              hipStream_t stream) {
    const float* control = (const float*)d_in[0];  // (32, 64, 1024)
    const float* proj    = (const float*)d_in[1];  // (64, 256)
    const float* W_ih    = (const float*)d_in[2];  // (512, 256)
    const float* W_hh    = (const float*)d_in[3];  // (512, 512)
    const float* W_out   = (const float*)d_in[4];  // (1024, 512)
    float* out = (float*)d_out;                    // 32 * 1024 * 1024 f32

    // workspace carve
    const size_t XW_B   = (size_t)BATCH * TSTEPS * HID * 4;     // 64 MiB
    const size_t MT_B   = (size_t)HID * CPD * 4;                // 128 KiB
    const size_t HS_B   = (size_t)BATCH * TSTEPS * HID * 2;     // 32 MiB
    const size_t WO_B   = (size_t)WIN * HID * 2;                // 1 MiB
    if (ws_size < XW_B + MT_B + HS_B + WO_B) return;

    char* ws = (char*)d_ws;
    float* xw = (float*)ws;                          ws += XW_B;
    float* M_t = (float*)ws;                         ws += MT_B;
    _Float16* hs = (_Float16*)ws;                    ws += HS_B;
    _Float16* Wo = (_Float16*)ws;

    k_a1<<<CPD, 512, 0, stream>>>(proj, W_ih, M_t);
    k_cvt<<<512, 256, 0, stream>>>(W_out, Wo);
    k_a2<<<BATCH * 16, 512, 0, stream>>>(control, M_t, xw);
    k_scan<<<BATCH, 1024, 0, stream>>>(W_hh, xw, hs);
    k_outgemm<<<dim3(8, 256), 256, 0, stream>>>(hs, Wo, out);
}

// Round 4
// 1761.715 us; speedup vs baseline: 2.0023x; 1.2008x over previous
//
#include <hip/hip_runtime.h>

// Problem constants
#define BATCH   32
#define CPD     64
#define TSTEPS  1024
#define IN_DIM  256
#define HID     512
#define WIN     1024

typedef _Float16 half2_t __attribute__((ext_vector_type(2)));
typedef _Float16 f16x8   __attribute__((ext_vector_type(8)));
typedef float    f32x4   __attribute__((ext_vector_type(4)));

union F16x8U { f16x8 v; half2_t p[4]; };

__device__ __forceinline__ float tanh_fast(float x) {
    // tanh(x) = 1 - 2/(e^{2x}+1); exact at +-inf, ~1e-7 abs err in range
    float e = __expf(2.0f * x);
    return 1.0f - 2.0f / (e + 1.0f);
}

// DPP cross-lane mov: returns partner lane's x per CTRL (within 16-lane row)
template <int CTRL>
__device__ __forceinline__ float dpp_xor_f32(float x) {
    return __int_as_float(
        __builtin_amdgcn_update_dpp(0, __float_as_int(x), CTRL, 0xf, 0xf, true));
}
#define DPP_XOR1 0xB1   // quad_perm [1,0,3,2]
#define DPP_XOR2 0x4E   // quad_perm [2,3,0,1]
#define DPP_XOR8 0x128  // row_ror:8  (== xor8 within 16-lane row)

// ---------------- A1: M_t[h][c] = sum_i proj[c][i] * W_ih[h][i] ----------------
__global__ __launch_bounds__(512) void k_a1(const float* __restrict__ proj,
                                            const float* __restrict__ W_ih,
                                            float* __restrict__ M_t) {
    __shared__ float p[IN_DIM];
    int c = blockIdx.x;                       // 64 blocks
    if (threadIdx.x < IN_DIM) p[threadIdx.x] = proj[c * IN_DIM + threadIdx.x];
    __syncthreads();
    int h = threadIdx.x;                      // 512 threads
    const float4* wr = (const float4*)(W_ih + (size_t)h * IN_DIM);
    float acc = 0.f;
#pragma unroll
    for (int i = 0; i < IN_DIM / 4; ++i) {
        float4 v = wr[i];
        acc += v.x * p[4*i] + v.y * p[4*i+1] + v.z * p[4*i+2] + v.w * p[4*i+3];
    }
    M_t[(size_t)h * CPD + c] = acc;           // [512][64]
}

// ---------------- C0: convert W_out f32 -> f16 ----------------
__global__ __launch_bounds__(256) void k_cvt(const float* __restrict__ src,
                                             _Float16* __restrict__ dst) {
    int i = (blockIdx.x * 256 + threadIdx.x) * 4;   // 512 blocks covers 524288
    float4 v = *(const float4*)(src + i);
    dst[i+0] = (_Float16)v.x; dst[i+1] = (_Float16)v.y;
    dst[i+2] = (_Float16)v.z; dst[i+3] = (_Float16)v.w;
}

// ---------------- A2: xw[b][t][h] = sum_c control[b][c][t] * M_t[h][c] ----------------
__global__ __launch_bounds__(512) void k_a2(const float* __restrict__ control,
                                            const float* __restrict__ M_t,
                                            float* __restrict__ xw) {
    __shared__ float ctl[CPD][68];            // padded, 16B-aligned rows
    int b  = blockIdx.x >> 4;                 // 32 batches
    int t0 = (blockIdx.x & 15) * 64;          // 16 t-blocks of 64
    int tid = threadIdx.x;                    // 512 threads

    // stage control tile (64 c x 64 t), coalesced float4 along t
    const float* gb = control + (size_t)b * CPD * TSTEPS + t0;
#pragma unroll
    for (int i = 0; i < 2; ++i) {
        int flat4 = tid * 2 + i;              // 0..1023 quads
        int c = flat4 >> 4, t4 = (flat4 & 15) * 4;
        float4 v = *(const float4*)(gb + (size_t)c * TSTEPS + t4);
        *(float4*)&ctl[c][t4] = v;
    }
    // M row into regs
    int h = tid;
    float mrow[CPD];
    const float4* mp = (const float4*)(M_t + (size_t)h * CPD);
#pragma unroll
    for (int i = 0; i < CPD / 4; ++i) {
        float4 v = mp[i];
        mrow[4*i] = v.x; mrow[4*i+1] = v.y; mrow[4*i+2] = v.z; mrow[4*i+3] = v.w;
    }
    __syncthreads();

    float* xo = xw + ((size_t)b * TSTEPS + t0) * HID + h;
#pragma unroll
    for (int half = 0; half < 2; ++half) {
        float acc[32];
#pragma unroll
        for (int q = 0; q < 32; ++q) acc[q] = 0.f;
#pragma unroll
        for (int c = 0; c < CPD; ++c) {
            float m = mrow[c];
#pragma unroll
            for (int q = 0; q < 8; ++q) {
                float4 v = *(const float4*)&ctl[c][half * 32 + q * 4];  // broadcast read
                acc[q*4+0] += v.x * m; acc[q*4+1] += v.y * m;
                acc[q*4+2] += v.z * m; acc[q*4+3] += v.w * m;
            }
        }
#pragma unroll
        for (int tt = 0; tt < 32; ++tt)
            xo[(size_t)(half * 32 + tt) * HID] = acc[tt];
    }
}

// ---------------- B: sequential recurrence, one WG per batch ----------------
// 32 WGs x 512 threads, waves_per_eu(2,2) -> 256 VGPR budget, 1 WG/CU (LDS).
// Thread tid = rb*16+cs owns W rows [rb*16, rb*16+16) x cols [cs*32, cs*32+32).
// Rows 0..11 in VGPR (192 half2 regs); rows 12..15 in LDS (128 KiB,
// [chunk][tid] f16x8 -> conflict-free b128). Per step: 256 fdot2 ->
// 4-stage distributed xor-reduce (DPP for xor1/2/8, shfl for xor4); final
// index algebra puts row == tid in each lane -> coalesced xw load/hs store.
#define HB_STRIDE 40
__global__ __launch_bounds__(512, 2)
__attribute__((amdgpu_waves_per_eu(2, 2)))
void k_scan(const float* __restrict__ W_hh,
            const float* __restrict__ xw,
            _Float16* __restrict__ hs) {
    const int b    = blockIdx.x;
    const int tid  = threadIdx.x;             // 512
    const int cs   = tid & 15;                // col slice
    const int rb   = tid >> 4;                // row block (16 rows)
    const int lane = tid & 63;

    // LDS: wlds[16][512] f16x8 (128 KiB) + h double buffer (~2.6 KiB)
    __shared__ __align__(16) f16x8    wlds[16 * 512];
    __shared__ __align__(16) _Float16 hb[2][16 * HB_STRIDE + 8];

    // ---- rows 0..11 into VGPRs: wreg[j][q] = W[rb*16+j][cs*32+2q..+1] ----
    half2_t wreg[12][16];
#pragma unroll
    for (int j = 0; j < 12; ++j) {
        const float* src = W_hh + (size_t)(rb * 16 + j) * HID + cs * 32;
#pragma unroll
        for (int q = 0; q < 16; q += 2) {
            float4 f = *(const float4*)(src + 2 * q);
            wreg[j][q]     = (half2_t){(_Float16)f.x, (_Float16)f.y};
            wreg[j][q + 1] = (half2_t){(_Float16)f.z, (_Float16)f.w};
        }
    }
    // ---- rows 12..15 into LDS: chunk r*4+qq holds cols [qq*8, qq*8+8) ----
#pragma unroll
    for (int r = 0; r < 4; ++r) {
        const float* src = W_hh + (size_t)(rb * 16 + 12 + r) * HID + cs * 32;
#pragma unroll
        for (int qq = 0; qq < 4; ++qq) {
            float4 f0 = *(const float4*)(src + qq * 8);
            float4 f1 = *(const float4*)(src + qq * 8 + 4);
            F16x8U u;
            u.p[0] = (half2_t){(_Float16)f0.x, (_Float16)f0.y};
            u.p[1] = (half2_t){(_Float16)f0.z, (_Float16)f0.w};
            u.p[2] = (half2_t){(_Float16)f1.x, (_Float16)f1.y};
            u.p[3] = (half2_t){(_Float16)f1.z, (_Float16)f1.w};
            wlds[((r * 4 + qq) << 9) + tid] = u.v;
        }
    }

    const bool b0 = lane & 1, b1 = lane & 2, b2 = lane & 4, b3 = lane & 8;
    const float* xwb = xw + (size_t)b * TSTEPS * HID;
    _Float16*    hsb = hs + (size_t)b * TSTEPS * HID;
    const int hbpos = (tid >> 5) * HB_STRIDE + (tid & 31);   // row 'tid' slot

    // ---- t = 0: h0 = tanh(xw[0][tid]) ----
    {
        float h0 = tanh_fast(xwb[tid]);
        _Float16 hf = (_Float16)h0;
        hb[0][hbpos] = hf;
        hsb[tid] = hf;
    }
    __syncthreads();

#pragma unroll 1
    for (int t = 1; t < TSTEPS; ++t) {
        // prefetch xw[t][tid] (consumed after the dot+reduce)
        float xwv = xwb[(size_t)t * HID + tid];

        const _Float16* rp = &hb[(t + 1) & 1][cs * HB_STRIDE];

        float a[16];
#pragma unroll
        for (int j = 0; j < 16; ++j) a[j] = 0.f;

        // ---- dot: a[i] = W[rb*16+i][cs*32..+32) . h[cs*32..+32) ----
#pragma unroll
        for (int qq = 0; qq < 4; ++qq) {
            F16x8U hu, wl0, wl1, wl2, wl3;
            hu.v  = *(const f16x8*)(rp + qq * 8);
            wl0.v = wlds[((0 * 4 + qq) << 9) + tid];
            wl1.v = wlds[((1 * 4 + qq) << 9) + tid];
            wl2.v = wlds[((2 * 4 + qq) << 9) + tid];
            wl3.v = wlds[((3 * 4 + qq) << 9) + tid];
#pragma unroll
            for (int q = 0; q < 4; ++q) {
                half2_t hh = hu.p[q];
#pragma unroll
                for (int j = 0; j < 12; ++j)
                    a[j] = __builtin_amdgcn_fdot2(wreg[j][qq * 4 + q], hh, a[j], false);
                a[12] = __builtin_amdgcn_fdot2(wl0.p[q], hh, a[12], false);
                a[13] = __builtin_amdgcn_fdot2(wl1.p[q], hh, a[13], false);
                a[14] = __builtin_amdgcn_fdot2(wl2.p[q], hh, a[14], false);
                a[15] = __builtin_amdgcn_fdot2(wl3.p[q], hh, a[15], false);
            }
        }

        // ---- 4-stage distributed xor-reduce over 16 col-slices ----
        // final: a[0] = full sum of row rb*16 + (lane&15) == tid
#pragma unroll
        for (int j = 0; j < 8; ++j) {          // xor1 (DPP quad_perm)
            float snd = b0 ? a[2 * j] : a[2 * j + 1];
            float kp  = b0 ? a[2 * j + 1] : a[2 * j];
            a[j] = kp + dpp_xor_f32<DPP_XOR1>(snd);
        }
#pragma unroll
        for (int j = 0; j < 4; ++j) {          // xor2 (DPP quad_perm)
            float snd = b1 ? a[2 * j] : a[2 * j + 1];
            float kp  = b1 ? a[2 * j + 1] : a[2 * j];
            a[j] = kp + dpp_xor_f32<DPP_XOR2>(snd);
        }
#pragma unroll
        for (int j = 0; j < 2; ++j) {          // xor4 (ds_swizzle via shfl)
            float snd = b2 ? a[2 * j] : a[2 * j + 1];
            float kp  = b2 ? a[2 * j + 1] : a[2 * j];
            a[j] = kp + __shfl_xor(snd, 4, 64);
        }
        {                                      // xor8 (DPP row_ror:8)
            float snd = b3 ? a[0] : a[1];
            float kp  = b3 ? a[1] : a[0];
            a[0] = kp + dpp_xor_f32<DPP_XOR8>(snd);
        }

        // ---- activation + publish (row == tid: fully coalesced) ----
        float hval = tanh_fast(a[0] + xwv);
        _Float16 hfv = (_Float16)hval;
        hb[t & 1][hbpos] = hfv;
        hsb[(size_t)t * HID + tid] = hfv;
        __syncthreads();
    }
}

// ---------------- C: out[row][w] = sin( sum_h hs[row][h] * Wout[w][h] ) ----------------
// 128x128 tile, BK=32, 4 waves in 2x2 quadrants, f16 MFMA 16x16x32.
// Grid is (N-tiles, M-tiles) so consecutive blocks share the A panel (L2 reuse).
__global__ void k_outgemm(const _Float16* __restrict__ hs,
                          const _Float16* __restrict__ Wo,
                          float* __restrict__ out) {
    __shared__ _Float16 Ap[128][40];          // +8 pad: conflict-free frag reads
    __shared__ _Float16 Bp[128][40];
    int tid = threadIdx.x;
    int r0 = blockIdx.y * 128;                // 256 M-tiles
    int c0 = blockIdx.x * 128;                // 8 N-tiles
    int wid = tid >> 6, l = tid & 63;
    int wr = (wid >> 1) * 64, wc = (wid & 1) * 64;
    int lrow = tid & 127, lhalf = (tid >> 7) * 16;   // staging assignment
    int fr = l & 15, kg = (l >> 4) * 8;

    f32x4 acc[4][4];
#pragma unroll
    for (int m = 0; m < 4; ++m)
#pragma unroll
        for (int n = 0; n < 4; ++n) acc[m][n] = (f32x4){0.f, 0.f, 0.f, 0.f};

    for (int k0 = 0; k0 < HID; k0 += 32) {
        const uint4* ga = (const uint4*)(hs + (size_t)(r0 + lrow) * HID + k0 + lhalf);
        uint4 a0 = ga[0], a1 = ga[1];
        const uint4* gbp = (const uint4*)(Wo + (size_t)(c0 + lrow) * HID + k0 + lhalf);
        uint4 b0 = gbp[0], b1 = gbp[1];
        __syncthreads();                      // prev-iter reads done
        *(uint4*)&Ap[lrow][lhalf] = a0; *(uint4*)&Ap[lrow][lhalf + 8] = a1;
        *(uint4*)&Bp[lrow][lhalf] = b0; *(uint4*)&Bp[lrow][lhalf + 8] = b1;
        __syncthreads();

        f16x8 af[4], bf[4];
#pragma unroll
        for (int m = 0; m < 4; ++m) af[m] = *(const f16x8*)&Ap[wr + m * 16 + fr][kg];
#pragma unroll
        for (int n = 0; n < 4; ++n) bf[n] = *(const f16x8*)&Bp[wc + n * 16 + fr][kg];
#pragma unroll
        for (int m = 0; m < 4; ++m)
#pragma unroll
            for (int n = 0; n < 4; ++n)
                acc[m][n] = __builtin_amdgcn_mfma_f32_16x16x32_f16(af[m], bf[n], acc[m][n], 0, 0, 0);
    }

    int fq = l >> 4;
#pragma unroll
    for (int m = 0; m < 4; ++m)
#pragma unroll
        for (int n = 0; n < 4; ++n)
#pragma unroll
            for (int q = 0; q < 4; ++q) {
                int row = r0 + wr + m * 16 + fq * 4 + q;
                int col = c0 + wc + n * 16 + fr;
                out[(size_t)row * WIN + col] = __sinf(acc[m][n][q]);
            }
}

// ---------------- launch ----------------
extern "C" void kernel_launch(void* const* d_in, const int* in_sizes, int n_in,
                              void* d_out, int out_size, void* d_ws, size_t ws_size,
                              hipStream_t stream) {
    const float* control = (const float*)d_in[0];  // (32, 64, 1024)
    const float* proj    = (const float*)d_in[1];  // (64, 256)
    const float* W_ih    = (const float*)d_in[2];  // (512, 256)
    const float* W_hh    = (const float*)d_in[3];  // (512, 512)
    const float* W_out   = (const float*)d_in[4];  // (1024, 512)
    float* out = (float*)d_out;                    // 32 * 1024 * 1024 f32

    // workspace carve
    const size_t XW_B   = (size_t)BATCH * TSTEPS * HID * 4;     // 64 MiB
    const size_t MT_B   = (size_t)HID * CPD * 4;                // 128 KiB
    const size_t HS_B   = (size_t)BATCH * TSTEPS * HID * 2;     // 32 MiB
    const size_t WO_B   = (size_t)WIN * HID * 2;                // 1 MiB
    if (ws_size < XW_B + MT_B + HS_B + WO_B) return;

    char* ws = (char*)d_ws;
    float* xw = (float*)ws;                          ws += XW_B;
    float* M_t = (float*)ws;                         ws += MT_B;
    _Float16* hs = (_Float16*)ws;                    ws += HS_B;
    _Float16* Wo = (_Float16*)ws;

    k_a1<<<CPD, 512, 0, stream>>>(proj, W_ih, M_t);
    k_cvt<<<512, 256, 0, stream>>>(W_out, Wo);
    k_a2<<<BATCH * 16, 512, 0, stream>>>(control, M_t, xw);
    k_scan<<<BATCH, 512, 0, stream>>>(W_hh, xw, hs);
    k_outgemm<<<dim3(8, 256), 256, 0, stream>>>(hs, Wo, out);
}